// Round 16
// baseline (1373.516 us; speedup 1.0000x reference)
//
#include <hip/hip_runtime.h>
#include <hip/hip_bf16.h>

#define TOK 49
#define NPT 2401                  // TOK*TOK
#define CDIM 384
#define NH 12
#define HDIM 32
#define NWIN 64
#define BTOT 4096
#define OUTSZ (BTOT * TOK * CDIM) // 77,070,336 floats per slab
#define L2E 1.4426950408889634f

typedef __attribute__((ext_vector_type(8))) short bf16x8;
typedef __attribute__((ext_vector_type(4))) float f32x4;
typedef unsigned int uint32;
typedef unsigned short ushort_t;

__device__ inline ushort_t f2bf(float f) {          // RNE fp32 -> bf16
  uint32 u = __float_as_uint(f);
  u += 0x7FFF + ((u >> 16) & 1);
  return (ushort_t)(u >> 16);
}
__device__ inline uint32 pk2(float a, float b) {    // v_cvt_pk_bf16_f32
  union { __hip_bfloat162 h; uint32 u; } x;
  x.h = __float22bfloat162_rn(float2{a, b});
  return x.u;
}
__device__ inline float bf2f(uint32 u) { return __uint_as_float((u & 0xffffu) << 16); }
__device__ inline bf16x8 pack8(float4 a, float4 b) {
  union { __hip_bfloat162 h[4]; bf16x8 v; } u;
  u.h[0] = __float22bfloat162_rn(float2{a.x, a.y});
  u.h[1] = __float22bfloat162_rn(float2{a.z, a.w});
  u.h[2] = __float22bfloat162_rn(float2{b.x, b.y});
  u.h[3] = __float22bfloat162_rn(float2{b.z, b.w});
  return u.v;
}
__device__ inline bf16x8 pack8f(const float* f) {
  union { __hip_bfloat162 h[4]; bf16x8 v; } u;
#pragma unroll
  for (int i = 0; i < 4; ++i) u.h[i] = __float22bfloat162_rn(float2{f[2*i], f[2*i+1]});
  return u.v;
}

// ---------------------------------------------------------------------------
// fp32 -> bf16 bulk convert (x, qkv_w, projw)
// ---------------------------------------------------------------------------
__global__ void k_cvt(const float* __restrict__ src, ushort_t* __restrict__ dst, int n8) {
  int i = blockIdx.x * 256 + threadIdx.x;
  if (i >= n8) return;
  const float4* s = (const float4*)(src + (size_t)i * 8);
  float4 a = s[0], b = s[1];
  uint4 o;
  o.x = (uint32)f2bf(a.x) | ((uint32)f2bf(a.y) << 16);
  o.y = (uint32)f2bf(a.z) | ((uint32)f2bf(a.w) << 16);
  o.z = (uint32)f2bf(b.x) | ((uint32)f2bf(b.y) << 16);
  o.w = (uint32)f2bf(b.z) | ((uint32)f2bf(b.w) << 16);
  *(uint4*)(dst + (size_t)i * 8) = o;
}

// ---------------------------------------------------------------------------
// biasmix[rid][16] = (plb[g] + sum_h plw[g,h]*rpb[rid,h]) * log2(e);  0 for g>=12
// ---------------------------------------------------------------------------
__global__ void k_bias(const float* __restrict__ rpb, const float* __restrict__ plw,
                       const float* __restrict__ plb, float* __restrict__ bm) {
  int i = blockIdx.x * 256 + threadIdx.x;
  if (i >= 169 * 16) return;
  int rid = i >> 4, g = i & 15;
  float s = 0.f;
  if (g < NH) {
    s = plb[g];
#pragma unroll
    for (int h = 0; h < NH; ++h) s = fmaf(plw[g * NH + h], rpb[rid * NH + h], s);
    s *= L2E;
  }
  bm[i] = s;
}

// ---------------------------------------------------------------------------
// Kernel 1: QKV GEMM, bf16 MFMA, 128x128, reg-staged + XCD swizzle (verified).
// ---------------------------------------------------------------------------
__launch_bounds__(256)
__global__ void k_qkv_mfma(const ushort_t* __restrict__ Xb, const ushort_t* __restrict__ Wb,
                           const float* __restrict__ Bq, float* __restrict__ qslab) {
  __shared__ ushort_t As[128 * 32];
  __shared__ ushort_t Bs[128 * 32];
  const int bid = blockIdx.x;                 // 0..14111 (14112 % 8 == 0)
  const int sw = (bid & 7) * 1764 + (bid >> 3);
  const int bx = sw / 9;
  const int by = sw - bx * 9;
  const int tid = threadIdx.x;
  const int l = tid & 63;
  const int wv = tid >> 6;
  const int wr = wv >> 1, wc = wv & 1;
  const int row0 = bx * 128;
  const int col0 = by * 128;

  f32x4 acc[4][4];
#pragma unroll
  for (int i = 0; i < 4; ++i)
#pragma unroll
    for (int j = 0; j < 4; ++j)
#pragma unroll
      for (int e = 0; e < 4; ++e) acc[i][j][e] = 0.f;

  for (int kb = 0; kb < CDIM; kb += 32) {
#pragma unroll
    for (int i = 0; i < 2; ++i) {
      int cid = tid + i * 256;
      int r = cid >> 2, c = cid & 3;
      uint4 v = *(const uint4*)&Xb[(size_t)(row0 + r) * CDIM + kb + c * 8];
      *(uint4*)&As[r * 32 + c * 8] = v;
      uint4 w = *(const uint4*)&Wb[(size_t)(col0 + r) * CDIM + kb + c * 8];
      *(uint4*)&Bs[r * 32 + c * 8] = w;
    }
    __syncthreads();
    bf16x8 af[4], bfr[4];
#pragma unroll
    for (int mt = 0; mt < 4; ++mt)
      af[mt] = *(const bf16x8*)&As[(wr * 64 + mt * 16 + (l & 15)) * 32 + (l >> 4) * 8];
#pragma unroll
    for (int nt = 0; nt < 4; ++nt)
      bfr[nt] = *(const bf16x8*)&Bs[(wc * 64 + nt * 16 + (l & 15)) * 32 + (l >> 4) * 8];
#pragma unroll
    for (int mt = 0; mt < 4; ++mt)
#pragma unroll
      for (int nt = 0; nt < 4; ++nt)
        acc[mt][nt] = __builtin_amdgcn_mfma_f32_16x16x32_bf16(af[mt], bfr[nt], acc[mt][nt], 0, 0, 0);
    __syncthreads();
  }

  const int slab = by / 3;
  const int cslab0 = col0 - slab * CDIM;
  float* dst = qslab + (size_t)slab * OUTSZ;
#pragma unroll
  for (int nt = 0; nt < 4; ++nt) {
    int colg = col0 + wc * 64 + nt * 16 + (l & 15);
    int colo = cslab0 + wc * 64 + nt * 16 + (l & 15);
    float bv = Bq[colg];
#pragma unroll
    for (int mt = 0; mt < 4; ++mt) {
      int rbase = row0 + wr * 64 + mt * 16 + (l >> 4) * 4;
#pragma unroll
      for (int j = 0; j < 4; ++j)
        dst[(size_t)(rbase + j) * CDIM + colo] = acc[mt][nt][j] + bv;
    }
  }
}

// ---------------------------------------------------------------------------
// Kernel 2 (v11): attention + fused out-proj, operand-swapped epilogue.
// Proj: D[c][n] = W-frag (A) x AO-frag (B) -> reg quad = 4 consecutive output
// cols at fixed row n -> float4 stores, float4 bias, per-lane n<NR guard.
// W-frag loaded once per (ct,ks), reused for both n-tiles (no traffic change).
// ---------------------------------------------------------------------------
__launch_bounds__(1024, 8)
__global__ void k_attn11(const float* __restrict__ qslab, const float* __restrict__ kslab,
                         const float* __restrict__ vslab, const float* __restrict__ mask,
                         const float* __restrict__ bmg, const int* __restrict__ relidx,
                         const float* __restrict__ plw, const float* __restrict__ pww,
                         const float* __restrict__ pwb, const ushort_t* __restrict__ Wb2,
                         const float* __restrict__ pjb, float* __restrict__ xout) {
  __shared__ __align__(16) ushort_t SA[19976];            // 39,952 B (S/P -> Vt -> AO)
  __shared__ __align__(16) ushort_t PP[12 * 1400 + 416];  // 34,432 B
  __shared__ __align__(16) ushort_t bm16[169 * 12 + 4];   //  4,064 B
  __shared__ ushort_t ridx_s[1240];                       //  2,480 B

  const int tid = threadIdx.x;
  const int b  = blockIdx.x >> 1;
  const int bh = blockIdx.x & 1;
  const int n0 = bh * 25;
  const int NR = bh ? 24 : 25;
  const size_t base = (size_t)b * TOK * CDIM;
  const int l = tid & 63, l15 = l & 15, l16 = l >> 4;
  const int wv = tid >> 6;                // 0..15
  const float SCL = 0.17677669529663687f * L2E;

  // ---- preamble
  for (int i = tid; i < 169 * 12; i += 1024) {
    int rid = i / 12, g = i - rid * 12;
    bm16[i] = f2bf(bmg[rid * 16 + g]);
  }
  for (int i = tid; i < 1240; i += 1024) {
    int pg = i + n0 * 49; if (pg > 2400) pg = 2400;
    ridx_s[i] = (ushort_t)relidx[pg];
  }
  for (int p = tid; p < 1240; p += 1024) *(uint2*)&SA[p * 16 + 12] = uint2{0u, 0u};
  if (tid < 580) *(uint32*)&SA[18816 + tid * 2] = 0u;   // pts 1176..1239 + tail pad
  if (tid < 208) *(uint32*)&PP[12 * 1400 + tid * 2] = 0u;

  // ---- Phase A: S[pl][h] = raw q.k for this block's rows
  {
    const int art = wv >> 3;           // 0..1 local n-tile
    const int act = (wv >> 1) & 3;     // m-tile
    const int ah0 = (wv & 1) * 6;      // head half
    const int nrow = art * 16 + l15;
    const int mrow = act * 16 + l15;
    const bool qv = nrow < NR;
    const bool kv = mrow < TOK;
#pragma unroll
    for (int hp = 0; hp < 3; ++hp) {
      f32x4 s2[2];
#pragma unroll
      for (int hh = 0; hh < 2; ++hh) {
        int h = ah0 + hp * 2 + hh;
        bf16x8 af = {0,0,0,0,0,0,0,0}, bf = {0,0,0,0,0,0,0,0};
        if (qv) {
          const float4* qp = (const float4*)(qslab + base + (size_t)(n0 + nrow) * CDIM + h * HDIM + l16 * 8);
          af = pack8(qp[0], qp[1]);
        }
        if (kv) {
          const float4* kp = (const float4*)(kslab + base + (size_t)mrow * CDIM + h * HDIM + l16 * 8);
          bf = pack8(kp[0], kp[1]);
        }
        f32x4 z = {0.f, 0.f, 0.f, 0.f};
        s2[hh] = __builtin_amdgcn_mfma_f32_16x16x32_bf16(af, bf, z, 0, 0, 0);
      }
#pragma unroll
      for (int j = 0; j < 4; ++j) {
        int nj = art * 16 + l16 * 4 + j;
        if (nj < NR && kv)
          *(uint32*)&SA[(nj * 49 + mrow) * 16 + ah0 + hp * 2] = pk2(s2[0][j], s2[1][j]);
      }
    }
  }
  __syncthreads();   // b1

  // ---- per-row: mix1 + softmax + mix2 (rows nl = wv, wv+16 while < NR)
  {
    const float* maskw = mask + (size_t)(b & (NWIN - 1)) * NPT;
    float apf[8], bpf[8];
#pragma unroll
    for (int j = 0; j < 8; ++j) {
      int kj = l16 * 8 + j;
      apf[j] = (l15 < NH && kj < NH) ? plw[l15 * NH + kj] * SCL : 0.f;
      bpf[j] = (l15 < NH && kj < NH) ? pww[l15 * NH + kj] : 0.f;
    }
    const bf16x8 aplw = pack8f(apf);
    const bf16x8 bpww = pack8f(bpf);
    const float pwbv = (l15 < NH) ? pwb[l15] : 0.f;

    for (int nl = wv; nl < NR; nl += 16) {
      const int pb0 = nl * 49;
      float ev[4][4];
      float rs[4] = {0.f, 0.f, 0.f, 0.f};
#pragma unroll
      for (int mc = 0; mc < 4; ++mc) {
        int m = mc * 16 + l15;
        int pl = pb0 + m;                         // <= 1239 (pads zeroed)
        bf16x8 sf = {0,0,0,0,0,0,0,0};            // K 16..31 MUST be 0
        if (l16 < 2) sf = *(const bf16x8*)&SA[pl * 16 + l16 * 8];
        int rid = (int)ridx_s[pl];
        uint2 bmu = *(const uint2*)&bm16[rid * 12 + l16 * 4];
        int pg = pl + n0 * 49; if (pg > 2400) pg = 2400;
        float mk = maskw[pg] * L2E;
        f32x4 cini = {bf2f(bmu.x) + mk, bf2f(bmu.x >> 16) + mk,
                      bf2f(bmu.y) + mk, bf2f(bmu.y >> 16) + mk};
        f32x4 o = __builtin_amdgcn_mfma_f32_16x16x32_bf16(aplw, sf, cini, 0, 0, 0);
        bool okm = (m < TOK);
#pragma unroll
        for (int j = 0; j < 4; ++j) {
          int g = l16 * 4 + j;
          float e = (okm && g < NH) ? exp2f(o[j]) : 0.f;
          ev[mc][j] = e;
          rs[j] += e;
        }
      }
#pragma unroll
      for (int d = 1; d < 16; d <<= 1)
#pragma unroll
        for (int j = 0; j < 4; ++j) rs[j] += __shfl_xor(rs[j], d, 64);
      float inv[4];
#pragma unroll
      for (int j = 0; j < 4; ++j) inv[j] = (rs[j] > 0.f) ? 1.f / rs[j] : 0.f;

      // P in place over S (own row only)
#pragma unroll
      for (int mc = 0; mc < 4; ++mc) {
        int m = mc * 16 + l15;
        if (m < TOK) {
          uint2 w;
          w.x = pk2(ev[mc][0] * inv[0], ev[mc][1] * inv[1]);
          w.y = pk2(ev[mc][2] * inv[2], ev[mc][3] * inv[3]);
          *(uint2*)&SA[(pb0 + m) * 16 + l16 * 4] = w;
        }
      }
      // mix2: rows=m, cols=g'
#pragma unroll
      for (int mc = 0; mc < 4; ++mc) {
        bf16x8 pf8 = {0,0,0,0,0,0,0,0};           // K 16..31 MUST be 0
        if (l16 < 2) pf8 = *(const bf16x8*)&SA[(pb0 + mc * 16 + l15) * 16 + l16 * 8];
        f32x4 cd = {pwbv, pwbv, pwbv, pwbv};
        f32x4 o = __builtin_amdgcn_mfma_f32_16x16x32_bf16(pf8, bpww, cd, 0, 0, 0);
        int m0 = mc * 16 + l16 * 4;
        if (l15 < NH && m0 < 56) {
          float z0 = (m0     < TOK) ? o[0] : 0.f;
          float z1 = (m0 + 1 < TOK) ? o[1] : 0.f;
          float z2 = (m0 + 2 < TOK) ? o[2] : 0.f;
          float z3 = (m0 + 3 < TOK) ? o[3] : 0.f;
          uint2 w;
          w.x = pk2(z0, z1);
          w.y = pk2(z2, z3);
          *(uint2*)&PP[l15 * 1400 + nl * 56 + m0] = w;
        }
      }
    }
  }
  __syncthreads();   // b2 (SA's P-copy now dead; PP holds P')

  // ---- Vt staging into SA region: Vt[c][m], stride 52, m=49..51 zeroed
  {
    ushort_t* Vt = SA;
    for (int i = tid; i < CDIM * 13; i += 1024) {
      int mq = i / CDIM, c = i - mq * CDIM;
      int m = mq * 4;
      float f0 = (m     < TOK) ? vslab[base + (size_t)(m    ) * CDIM + c] : 0.f;
      float f1 = (m + 1 < TOK) ? vslab[base + (size_t)(m + 1) * CDIM + c] : 0.f;
      float f2 = (m + 2 < TOK) ? vslab[base + (size_t)(m + 2) * CDIM + c] : 0.f;
      float f3 = (m + 3 < TOK) ? vslab[base + (size_t)(m + 3) * CDIM + c] : 0.f;
      uint2 u;
      u.x = pk2(f0, f1);
      u.y = pk2(f2, f3);
      *(uint2*)&Vt[c * 52 + mq * 4] = u;
    }
  }
  __syncthreads();   // b3

  // ---- Phase E: PV (compute only; results held in regs across b4)
  f32x4 acc3[3];
  const int ert = wv >> 3;
  const int edt = (wv >> 2) & 1;
  const int egq = wv & 3;
  {
    const ushort_t* Vt = SA;
#pragma unroll
    for (int gi = 0; gi < 3; ++gi) {
      int g = egq * 3 + gi;
      int col = g * HDIM + edt * 16 + l15;
      f32x4 acc = {0.f, 0.f, 0.f, 0.f};
#pragma unroll
      for (int ks = 0; ks < 2; ++ks) {
        bf16x8 pa8 = {0,0,0,0,0,0,0,0};
        bf16x8 vb8 = {0,0,0,0,0,0,0,0};
        if (!(ks == 1 && l16 == 3)) {             // k-slots 56..63 virtual pad
          pa8 = *(const bf16x8*)&PP[g * 1400 + (ert * 16 + l15) * 56 + ks * 32 + l16 * 8];
          uint2 lo = *(const uint2*)&Vt[col * 52 + ks * 32 + l16 * 8];
          uint2 hi = *(const uint2*)&Vt[col * 52 + ks * 32 + l16 * 8 + 4];
          union { uint32 u[4]; bf16x8 v; } uv;
          uv.u[0] = lo.x; uv.u[1] = lo.y; uv.u[2] = hi.x; uv.u[3] = hi.y;
          vb8 = uv.v;
        }
        acc = __builtin_amdgcn_mfma_f32_16x16x32_bf16(pa8, vb8, acc, 0, 0, 0);
      }
      acc3[gi] = acc;
    }
  }
  __syncthreads();   // b4: all Vt reads complete

  // ---- AO: attention output bf16 [32][392] into SA (overwrites Vt)
  {
    ushort_t* AO = SA;
#pragma unroll
    for (int gi = 0; gi < 3; ++gi) {
      int g = egq * 3 + gi;
      int col = g * HDIM + edt * 16 + l15;
#pragma unroll
      for (int j = 0; j < 4; ++j) {
        int nlo = ert * 16 + l16 * 4 + j;         // 0..31, all rows covered
        AO[nlo * 392 + col] = f2bf(acc3[gi][j]);
      }
    }
  }
  __syncthreads();   // b5

  // ---- fused out-proj, operand-swapped: D[c][n] = W (A) x AO (B)
  {
    const ushort_t* AO = SA;
    f32x4 pacc[2][2];                             // [nt][ci]
#pragma unroll
    for (int r = 0; r < 2; ++r)
#pragma unroll
      for (int c = 0; c < 2; ++c)
#pragma unroll
        for (int e = 0; e < 4; ++e) pacc[r][c][e] = 0.f;

    const bool two = (wv < 8);                    // waves 0..7 cover a 2nd col-tile
    for (int ks = 0; ks < 12; ++ks) {
      bf16x8 ao0 = *(const bf16x8*)&AO[(l15     ) * 392 + ks * 32 + l16 * 8];
      bf16x8 ao1 = *(const bf16x8*)&AO[(16 + l15) * 392 + ks * 32 + l16 * 8];
      {
        uint4 wq = *(const uint4*)&Wb2[(size_t)(wv * 16 + l15) * CDIM + ks * 32 + l16 * 8];
        union { uint4 u; bf16x8 v; } uw; uw.u = wq;
        pacc[0][0] = __builtin_amdgcn_mfma_f32_16x16x32_bf16(uw.v, ao0, pacc[0][0], 0, 0, 0);
        pacc[1][0] = __builtin_amdgcn_mfma_f32_16x16x32_bf16(uw.v, ao1, pacc[1][0], 0, 0, 0);
      }
      if (two) {
        uint4 wq = *(const uint4*)&Wb2[(size_t)((wv + 16) * 16 + l15) * CDIM + ks * 32 + l16 * 8];
        union { uint4 u; bf16x8 v; } uw; uw.u = wq;
        pacc[0][1] = __builtin_amdgcn_mfma_f32_16x16x32_bf16(uw.v, ao0, pacc[0][1], 0, 0, 0);
        pacc[1][1] = __builtin_amdgcn_mfma_f32_16x16x32_bf16(uw.v, ao1, pacc[1][1], 0, 0, 0);
      }
    }
    // D[c][n]: reg j -> col c = ct*16 + l16*4 + j (contiguous), lane l15 -> row n
#pragma unroll
    for (int nt = 0; nt < 2; ++nt) {
      int n = nt * 16 + l15;
      if (n < NR) {
        {
          int c0 = wv * 16 + l16 * 4;
          float4 pb4 = *(const float4*)&pjb[c0];
          float4 o4 = {pacc[nt][0][0] + pb4.x, pacc[nt][0][1] + pb4.y,
                       pacc[nt][0][2] + pb4.z, pacc[nt][0][3] + pb4.w};
          *(float4*)&xout[base + (size_t)(n0 + n) * CDIM + c0] = o4;
        }
        if (two) {
          int c0 = (wv + 16) * 16 + l16 * 4;
          float4 pb4 = *(const float4*)&pjb[c0];
          float4 o4 = {pacc[nt][1][0] + pb4.x, pacc[nt][1][1] + pb4.y,
                       pacc[nt][1][2] + pb4.z, pacc[nt][1][3] + pb4.w};
          *(float4*)&xout[base + (size_t)(n0 + n) * CDIM + c0] = o4;
        }
      }
    }
  }
}

// ---------------------------------------------------------------------------
extern "C" void kernel_launch(void* const* d_in, const int* in_sizes, int n_in,
                              void* d_out, int out_size, void* d_ws, size_t ws_size,
                              hipStream_t stream) {
  const float* x      = (const float*)d_in[0];
  const float* mask   = (const float*)d_in[1];
  const float* qkv_w  = (const float*)d_in[2];
  const float* qkv_b  = (const float*)d_in[3];
  const float* rpb    = (const float*)d_in[4];
  const float* plw    = (const float*)d_in[5];
  const float* plb    = (const float*)d_in[6];
  const float* pww    = (const float*)d_in[7];
  const float* pwb    = (const float*)d_in[8];
  const float* projw  = (const float*)d_in[9];
  const float* projb  = (const float*)d_in[10];
  const int*   relidx = (const int*)d_in[11];

  float* out   = (float*)d_out;
  float* qslab = out + (size_t)OUTSZ;
  float* kslab = out + 2 * (size_t)OUTSZ;
  float* vslab = out + 3 * (size_t)OUTSZ;

  ushort_t* Xb  = (ushort_t*)out;                    // x bf16 (out-slab scratch)
  ushort_t* Wb  = (ushort_t*)(out + 70000000);       // qkv_w bf16 (out-slab scratch)
  float*    bm  = (float*)d_ws;                      // 169*16 f32 biasmix
  ushort_t* Wb2 = (ushort_t*)((float*)d_ws + 4096);  // projw bf16 (ws, survives attn)

  k_cvt<<<(OUTSZ / 8 + 255) / 256, 256, 0, stream>>>(x, Xb, OUTSZ / 8);
  k_cvt<<<(3 * CDIM * CDIM / 8 + 255) / 256, 256, 0, stream>>>(qkv_w, Wb, 3 * CDIM * CDIM / 8);
  k_cvt<<<(CDIM * CDIM / 8 + 255) / 256, 256, 0, stream>>>(projw, Wb2, CDIM * CDIM / 8);
  k_bias<<<(169 * 16 + 255) / 256, 256, 0, stream>>>(rpb, plw, plb, bm);

  k_qkv_mfma<<<(BTOT * TOK / 128) * 9, 256, 0, stream>>>(Xb, Wb, qkv_b, qslab);

  k_attn11<<<BTOT * 2, 1024, 0, stream>>>(qslab, kslab, vslab, mask, bm, relidx,
                                          plw, pww, pwb, Wb2, projb, out);
}

// Round 17
// 1330.341 us; speedup vs baseline: 1.0325x; 1.0325x over previous
//
#include <hip/hip_runtime.h>
#include <hip/hip_bf16.h>

#define TOK 49
#define NPT 2401                  // TOK*TOK
#define CDIM 384
#define NH 12
#define HDIM 32
#define NWIN 64
#define BTOT 4096
#define OUTSZ (BTOT * TOK * CDIM) // 77,070,336 floats per slab
#define L2E 1.4426950408889634f

typedef __attribute__((ext_vector_type(8))) short bf16x8;
typedef __attribute__((ext_vector_type(4))) float f32x4;
typedef unsigned int uint32;
typedef unsigned short ushort_t;

__device__ inline ushort_t f2bf(float f) {          // RNE fp32 -> bf16
  uint32 u = __float_as_uint(f);
  u += 0x7FFF + ((u >> 16) & 1);
  return (ushort_t)(u >> 16);
}
__device__ inline uint32 pk2(float a, float b) {    // v_cvt_pk_bf16_f32
  union { __hip_bfloat162 h; uint32 u; } x;
  x.h = __float22bfloat162_rn(float2{a, b});
  return x.u;
}
__device__ inline float bf2f(uint32 u) { return __uint_as_float((u & 0xffffu) << 16); }
__device__ inline bf16x8 pack8(float4 a, float4 b) {
  union { __hip_bfloat162 h[4]; bf16x8 v; } u;
  u.h[0] = __float22bfloat162_rn(float2{a.x, a.y});
  u.h[1] = __float22bfloat162_rn(float2{a.z, a.w});
  u.h[2] = __float22bfloat162_rn(float2{b.x, b.y});
  u.h[3] = __float22bfloat162_rn(float2{b.z, b.w});
  return u.v;
}
__device__ inline bf16x8 pack8f(const float* f) {
  union { __hip_bfloat162 h[4]; bf16x8 v; } u;
#pragma unroll
  for (int i = 0; i < 4; ++i) u.h[i] = __float22bfloat162_rn(float2{f[2*i], f[2*i+1]});
  return u.v;
}

// ---------------------------------------------------------------------------
// fp32 -> bf16 bulk convert (x, qkv_w)
// ---------------------------------------------------------------------------
__global__ void k_cvt(const float* __restrict__ src, ushort_t* __restrict__ dst, int n8) {
  int i = blockIdx.x * 256 + threadIdx.x;
  if (i >= n8) return;
  const float4* s = (const float4*)(src + (size_t)i * 8);
  float4 a = s[0], b = s[1];
  uint4 o;
  o.x = (uint32)f2bf(a.x) | ((uint32)f2bf(a.y) << 16);
  o.y = (uint32)f2bf(a.z) | ((uint32)f2bf(a.w) << 16);
  o.z = (uint32)f2bf(b.x) | ((uint32)f2bf(b.y) << 16);
  o.w = (uint32)f2bf(b.z) | ((uint32)f2bf(b.w) << 16);
  *(uint4*)(dst + (size_t)i * 8) = o;
}

// ---------------------------------------------------------------------------
// Flat bias table: bmf[p][g] = (plb[g] + sum_h plw[g,h]*rpb[relidx[p],h])*log2e
// [2401][12] bf16 = 57.6 KB, window-independent, L2-resident for all blocks.
// ---------------------------------------------------------------------------
__global__ void k_bias2(const float* __restrict__ rpb, const float* __restrict__ plw,
                        const float* __restrict__ plb, const int* __restrict__ relidx,
                        ushort_t* __restrict__ bmf) {
  int i = blockIdx.x * 256 + threadIdx.x;
  if (i >= NPT * 12) return;
  int p = i / 12, g = i - (i / 12) * 12;
  int rid = relidx[p];
  float s = plb[g];
#pragma unroll
  for (int h = 0; h < NH; ++h) s = fmaf(plw[g * NH + h], rpb[rid * NH + h], s);
  bmf[i] = f2bf(s * L2E);
}

// ---------------------------------------------------------------------------
// Kernel 1: QKV GEMM, bf16 MFMA, 128x128, reg-staged + XCD swizzle (r13).
// ---------------------------------------------------------------------------
__launch_bounds__(256)
__global__ void k_qkv_mfma(const ushort_t* __restrict__ Xb, const ushort_t* __restrict__ Wb,
                           const float* __restrict__ Bq, float* __restrict__ qslab) {
  __shared__ ushort_t As[128 * 32];
  __shared__ ushort_t Bs[128 * 32];
  const int bid = blockIdx.x;                 // 0..14111 (14112 % 8 == 0)
  const int sw = (bid & 7) * 1764 + (bid >> 3);
  const int bx = sw / 9;
  const int by = sw - bx * 9;
  const int tid = threadIdx.x;
  const int l = tid & 63;
  const int wv = tid >> 6;
  const int wr = wv >> 1, wc = wv & 1;
  const int row0 = bx * 128;
  const int col0 = by * 128;

  f32x4 acc[4][4];
#pragma unroll
  for (int i = 0; i < 4; ++i)
#pragma unroll
    for (int j = 0; j < 4; ++j)
#pragma unroll
      for (int e = 0; e < 4; ++e) acc[i][j][e] = 0.f;

  for (int kb = 0; kb < CDIM; kb += 32) {
#pragma unroll
    for (int i = 0; i < 2; ++i) {
      int cid = tid + i * 256;
      int r = cid >> 2, c = cid & 3;
      uint4 v = *(const uint4*)&Xb[(size_t)(row0 + r) * CDIM + kb + c * 8];
      *(uint4*)&As[r * 32 + c * 8] = v;
      uint4 w = *(const uint4*)&Wb[(size_t)(col0 + r) * CDIM + kb + c * 8];
      *(uint4*)&Bs[r * 32 + c * 8] = w;
    }
    __syncthreads();
    bf16x8 af[4], bfr[4];
#pragma unroll
    for (int mt = 0; mt < 4; ++mt)
      af[mt] = *(const bf16x8*)&As[(wr * 64 + mt * 16 + (l & 15)) * 32 + (l >> 4) * 8];
#pragma unroll
    for (int nt = 0; nt < 4; ++nt)
      bfr[nt] = *(const bf16x8*)&Bs[(wc * 64 + nt * 16 + (l & 15)) * 32 + (l >> 4) * 8];
#pragma unroll
    for (int mt = 0; mt < 4; ++mt)
#pragma unroll
      for (int nt = 0; nt < 4; ++nt)
        acc[mt][nt] = __builtin_amdgcn_mfma_f32_16x16x32_bf16(af[mt], bfr[nt], acc[mt][nt], 0, 0, 0);
    __syncthreads();
  }

  const int slab = by / 3;
  const int cslab0 = col0 - slab * CDIM;
  float* dst = qslab + (size_t)slab * OUTSZ;
#pragma unroll
  for (int nt = 0; nt < 4; ++nt) {
    int colg = col0 + wc * 64 + nt * 16 + (l & 15);
    int colo = cslab0 + wc * 64 + nt * 16 + (l & 15);
    float bv = Bq[colg];
#pragma unroll
    for (int mt = 0; mt < 4; ++mt) {
      int rbase = row0 + wr * 64 + mt * 16 + (l >> 4) * 4;
#pragma unroll
      for (int j = 0; j < 4; ++j)
        dst[(size_t)(rbase + j) * CDIM + colo] = acc[mt][nt][j] + bv;
    }
  }
}

// ---------------------------------------------------------------------------
// Kernel 2 (v9b): r13's attn9 with the flat bias table. ridx_s/bm16 LDS
// arrays and their preamble loads deleted; mix1 reads one aligned uint2
// from global bmf (L2-resident) instead of the 2-level LDS lookup chain.
// All other r13 invariants unchanged (NaN audit identical).
// ---------------------------------------------------------------------------
__launch_bounds__(1024, 8)
__global__ void k_attn9(const float* __restrict__ qslab, const float* __restrict__ kslab,
                        const float* __restrict__ vslab, const float* __restrict__ mask,
                        const ushort_t* __restrict__ bmf, const float* __restrict__ plw,
                        const float* __restrict__ pww, const float* __restrict__ pwb,
                        float* __restrict__ xout) {
  __shared__ __align__(16) ushort_t SA[19976];            // 39,952 B (S/P -> Vt)
  __shared__ __align__(16) ushort_t PP[12 * 1400 + 416];  // 34,432 B

  const int tid = threadIdx.x;
  const int b  = blockIdx.x >> 1;
  const int bh = blockIdx.x & 1;
  const int n0 = bh * 25;
  const int NR = bh ? 24 : 25;
  const size_t base = (size_t)b * TOK * CDIM;
  const int l = tid & 63, l15 = l & 15, l16 = l >> 4;
  const int wv = tid >> 6;                // 0..15
  const float SCL = 0.17677669529663687f * L2E;

  // ---- preamble: zero S h-slots 12..15 + phantom tail rows
  for (int p = tid; p < 1240; p += 1024) *(uint2*)&SA[p * 16 + 12] = uint2{0u, 0u};
  if (tid < 580) *(uint32*)&SA[18816 + tid * 2] = 0u;   // pts 1176..1239 + tail pad
  if (tid < 208) *(uint32*)&PP[12 * 1400 + tid * 2] = 0u;

  // ---- Phase A: S[pl][h] = raw q.k for this block's rows
  {
    const int art = wv >> 3;           // 0..1 local n-tile
    const int act = (wv >> 1) & 3;     // m-tile
    const int ah0 = (wv & 1) * 6;      // head half
    const int nrow = art * 16 + l15;
    const int mrow = act * 16 + l15;
    const bool qv = nrow < NR;
    const bool kv = mrow < TOK;
#pragma unroll
    for (int hp = 0; hp < 3; ++hp) {
      f32x4 s2[2];
#pragma unroll
      for (int hh = 0; hh < 2; ++hh) {
        int h = ah0 + hp * 2 + hh;
        bf16x8 af = {0,0,0,0,0,0,0,0}, bf = {0,0,0,0,0,0,0,0};
        if (qv) {
          const float4* qp = (const float4*)(qslab + base + (size_t)(n0 + nrow) * CDIM + h * HDIM + l16 * 8);
          af = pack8(qp[0], qp[1]);
        }
        if (kv) {
          const float4* kp = (const float4*)(kslab + base + (size_t)mrow * CDIM + h * HDIM + l16 * 8);
          bf = pack8(kp[0], kp[1]);
        }
        f32x4 z = {0.f, 0.f, 0.f, 0.f};
        s2[hh] = __builtin_amdgcn_mfma_f32_16x16x32_bf16(af, bf, z, 0, 0, 0);
      }
#pragma unroll
      for (int j = 0; j < 4; ++j) {
        int nj = art * 16 + l16 * 4 + j;
        if (nj < NR && kv)
          *(uint32*)&SA[(nj * 49 + mrow) * 16 + ah0 + hp * 2] = pk2(s2[0][j], s2[1][j]);
      }
    }
  }
  __syncthreads();   // b1

  // ---- per-row: mix1 + softmax + mix2 (rows nl = wv, wv+16 while < NR)
  {
    const float* maskw = mask + (size_t)(b & (NWIN - 1)) * NPT;
    float apf[8], bpf[8];
#pragma unroll
    for (int j = 0; j < 8; ++j) {
      int kj = l16 * 8 + j;
      apf[j] = (l15 < NH && kj < NH) ? plw[l15 * NH + kj] * SCL : 0.f;
      bpf[j] = (l15 < NH && kj < NH) ? pww[l15 * NH + kj] : 0.f;
    }
    const bf16x8 aplw = pack8f(apf);
    const bf16x8 bpww = pack8f(bpf);
    const float pwbv = (l15 < NH) ? pwb[l15] : 0.f;

    for (int nl = wv; nl < NR; nl += 1024 / 64) {
      const int pb0 = nl * 49;
      float ev[4][4];
      float rs[4] = {0.f, 0.f, 0.f, 0.f};
#pragma unroll
      for (int mc = 0; mc < 4; ++mc) {
        int m = mc * 16 + l15;
        int pl = pb0 + m;                         // <= 1239 (pads zeroed)
        bf16x8 sf = {0,0,0,0,0,0,0,0};            // K 16..31 MUST be 0
        if (l16 < 2) sf = *(const bf16x8*)&SA[pl * 16 + l16 * 8];
        int pg = pl + n0 * 49; if (pg > 2400) pg = 2400;
        uint2 bmu = *(const uint2*)&bmf[pg * 12 + l16 * 4];   // flat bias, L2-hit
        float mk = maskw[pg] * L2E;
        f32x4 cini = {bf2f(bmu.x) + mk, bf2f(bmu.x >> 16) + mk,
                      bf2f(bmu.y) + mk, bf2f(bmu.y >> 16) + mk};
        f32x4 o = __builtin_amdgcn_mfma_f32_16x16x32_bf16(aplw, sf, cini, 0, 0, 0);
        bool okm = (m < TOK);
#pragma unroll
        for (int j = 0; j < 4; ++j) {
          int g = l16 * 4 + j;
          float e = (okm && g < NH) ? exp2f(o[j]) : 0.f;
          ev[mc][j] = e;
          rs[j] += e;
        }
      }
#pragma unroll
      for (int d = 1; d < 16; d <<= 1)
#pragma unroll
        for (int j = 0; j < 4; ++j) rs[j] += __shfl_xor(rs[j], d, 64);
      float inv[4];
#pragma unroll
      for (int j = 0; j < 4; ++j) inv[j] = (rs[j] > 0.f) ? 1.f / rs[j] : 0.f;

      // P in place over S (own row only)
#pragma unroll
      for (int mc = 0; mc < 4; ++mc) {
        int m = mc * 16 + l15;
        if (m < TOK) {
          uint2 w;
          w.x = pk2(ev[mc][0] * inv[0], ev[mc][1] * inv[1]);
          w.y = pk2(ev[mc][2] * inv[2], ev[mc][3] * inv[3]);
          *(uint2*)&SA[(pb0 + m) * 16 + l16 * 4] = w;
        }
      }
      // mix2: rows=m, cols=g'
#pragma unroll
      for (int mc = 0; mc < 4; ++mc) {
        bf16x8 pf8 = {0,0,0,0,0,0,0,0};           // K 16..31 MUST be 0
        if (l16 < 2) pf8 = *(const bf16x8*)&SA[(pb0 + mc * 16 + l15) * 16 + l16 * 8];
        f32x4 cd = {pwbv, pwbv, pwbv, pwbv};
        f32x4 o = __builtin_amdgcn_mfma_f32_16x16x32_bf16(pf8, bpww, cd, 0, 0, 0);
        int m0 = mc * 16 + l16 * 4;
        if (l15 < NH && m0 < 56) {
          float z0 = (m0     < TOK) ? o[0] : 0.f;
          float z1 = (m0 + 1 < TOK) ? o[1] : 0.f;
          float z2 = (m0 + 2 < TOK) ? o[2] : 0.f;
          float z3 = (m0 + 3 < TOK) ? o[3] : 0.f;
          uint2 w;
          w.x = pk2(z0, z1);
          w.y = pk2(z2, z3);
          *(uint2*)&PP[l15 * 1400 + nl * 56 + m0] = w;
        }
      }
    }
  }
  __syncthreads();   // b2 (SA's P-copy now dead; PP holds P')

  // ---- Vt staging into SA region: Vt[c][m], stride 52, m=49..51 zeroed
  {
    ushort_t* Vt = SA;
    for (int i = tid; i < CDIM * 13; i += 1024) {
      int mq = i / CDIM, c = i - mq * CDIM;
      int m = mq * 4;
      float f0 = (m     < TOK) ? vslab[base + (size_t)(m    ) * CDIM + c] : 0.f;
      float f1 = (m + 1 < TOK) ? vslab[base + (size_t)(m + 1) * CDIM + c] : 0.f;
      float f2 = (m + 2 < TOK) ? vslab[base + (size_t)(m + 2) * CDIM + c] : 0.f;
      float f3 = (m + 3 < TOK) ? vslab[base + (size_t)(m + 3) * CDIM + c] : 0.f;
      uint2 u;
      u.x = pk2(f0, f1);
      u.y = pk2(f2, f3);
      *(uint2*)&Vt[c * 52 + mq * 4] = u;
    }
  }
  __syncthreads();   // b3

  // ---- Phase E: PV; wave=(ert, edt, egq) -> 3 heads; V from Vt (b64 pairs)
  {
    const ushort_t* Vt = SA;
    const int ert = wv >> 3;
    const int edt = (wv >> 2) & 1;
    const int egq = wv & 3;
#pragma unroll
    for (int gi = 0; gi < 3; ++gi) {
      int g = egq * 3 + gi;
      int col = g * HDIM + edt * 16 + l15;
      f32x4 acc = {0.f, 0.f, 0.f, 0.f};
#pragma unroll
      for (int ks = 0; ks < 2; ++ks) {
        bf16x8 pa8 = {0,0,0,0,0,0,0,0};
        bf16x8 vb8 = {0,0,0,0,0,0,0,0};
        if (!(ks == 1 && l16 == 3)) {             // k-slots 56..63 virtual pad
          pa8 = *(const bf16x8*)&PP[g * 1400 + (ert * 16 + l15) * 56 + ks * 32 + l16 * 8];
          uint2 lo = *(const uint2*)&Vt[col * 52 + ks * 32 + l16 * 8];
          uint2 hi = *(const uint2*)&Vt[col * 52 + ks * 32 + l16 * 8 + 4];
          union { uint32 u[4]; bf16x8 v; } uv;
          uv.u[0] = lo.x; uv.u[1] = lo.y; uv.u[2] = hi.x; uv.u[3] = hi.y;
          vb8 = uv.v;
        }
        acc = __builtin_amdgcn_mfma_f32_16x16x32_bf16(pa8, vb8, acc, 0, 0, 0);
      }
#pragma unroll
      for (int j = 0; j < 4; ++j) {
        int nlo = ert * 16 + l16 * 4 + j;
        if (nlo < NR)
          xout[base + (size_t)(n0 + nlo) * CDIM + col] = acc[j];
      }
    }
  }
}

// ---------------------------------------------------------------------------
// Kernel 3 (v3): output projection, 64-row strips, W LDS-staged (r11/r13).
// ---------------------------------------------------------------------------
__launch_bounds__(512, 4)
__global__ void k_proj3(float* __restrict__ Y, const float* __restrict__ W,
                        const float* __restrict__ Bv) {
  __shared__ __align__(16) ushort_t Asb[64 * 392];   // 50,176 B
  __shared__ __align__(16) ushort_t Bsb[384 * 40];   // 30,720 B
  const int tid = threadIdx.x;
  const int l = tid & 63, l15 = l & 15, l16 = l >> 4;
  const int wv = tid >> 6;
  const int wr = wv >> 2;
  const int wc = wv & 3;
  const int row0 = blockIdx.x * 64;

#pragma unroll
  for (int i = 0; i < 6; ++i) {
    int cid = tid + i * 512;
    int r = cid / 48, c8 = cid - (cid / 48) * 48;
    const float4* s = (const float4*)&Y[(size_t)(row0 + r) * CDIM + c8 * 8];
    float4 a = s[0], b = s[1];
    uint4 o;
    o.x = pk2(a.x, a.y); o.y = pk2(a.z, a.w);
    o.z = pk2(b.x, b.y); o.w = pk2(b.z, b.w);
    *(uint4*)&Asb[r * 392 + c8 * 8] = o;
  }

  f32x4 acc[2][6];
#pragma unroll
  for (int i = 0; i < 2; ++i)
#pragma unroll
    for (int j = 0; j < 6; ++j)
#pragma unroll
      for (int e = 0; e < 4; ++e) acc[i][j][e] = 0.f;

  for (int kb = 0; kb < 12; ++kb) {
    __syncthreads();
#pragma unroll
    for (int i = 0; i < 3; ++i) {
      int cid = tid + i * 512;
      int col = cid >> 2, k8 = cid & 3;
      const float4* s = (const float4*)&W[(size_t)col * CDIM + kb * 32 + k8 * 8];
      float4 a = s[0], b = s[1];
      uint4 o;
      o.x = pk2(a.x, a.y); o.y = pk2(a.z, a.w);
      o.z = pk2(b.x, b.y); o.w = pk2(b.z, b.w);
      *(uint4*)&Bsb[col * 40 + k8 * 8] = o;
    }
    __syncthreads();
    bf16x8 af[2], bfr[6];
#pragma unroll
    for (int mt = 0; mt < 2; ++mt)
      af[mt] = *(const bf16x8*)&Asb[(wr * 32 + mt * 16 + l15) * 392 + kb * 32 + l16 * 8];
#pragma unroll
    for (int nt = 0; nt < 6; ++nt)
      bfr[nt] = *(const bf16x8*)&Bsb[(wc * 96 + nt * 16 + l15) * 40 + l16 * 8];
#pragma unroll
    for (int mt = 0; mt < 2; ++mt)
#pragma unroll
      for (int nt = 0; nt < 6; ++nt)
        acc[mt][nt] = __builtin_amdgcn_mfma_f32_16x16x32_bf16(af[mt], bfr[nt], acc[mt][nt], 0, 0, 0);
  }

#pragma unroll
  for (int nt = 0; nt < 6; ++nt) {
    int col = wc * 96 + nt * 16 + l15;
    float bv = Bv[col];
#pragma unroll
    for (int mt = 0; mt < 2; ++mt) {
      int rbase = row0 + wr * 32 + mt * 16 + l16 * 4;
#pragma unroll
      for (int j = 0; j < 4; ++j)
        Y[(size_t)(rbase + j) * CDIM + col] = acc[mt][nt][j] + bv;
    }
  }
}

// ---------------------------------------------------------------------------
extern "C" void kernel_launch(void* const* d_in, const int* in_sizes, int n_in,
                              void* d_out, int out_size, void* d_ws, size_t ws_size,
                              hipStream_t stream) {
  const float* x      = (const float*)d_in[0];
  const float* mask   = (const float*)d_in[1];
  const float* qkv_w  = (const float*)d_in[2];
  const float* qkv_b  = (const float*)d_in[3];
  const float* rpb    = (const float*)d_in[4];
  const float* plw    = (const float*)d_in[5];
  const float* plb    = (const float*)d_in[6];
  const float* pww    = (const float*)d_in[7];
  const float* pwb    = (const float*)d_in[8];
  const float* projw  = (const float*)d_in[9];
  const float* projb  = (const float*)d_in[10];
  const int*   relidx = (const int*)d_in[11];

  float* out   = (float*)d_out;
  float* qslab = out + (size_t)OUTSZ;
  float* kslab = out + 2 * (size_t)OUTSZ;
  float* vslab = out + 3 * (size_t)OUTSZ;

  ushort_t* Xb  = (ushort_t*)out;                    // x bf16 (out-slab scratch)
  ushort_t* Wb  = (ushort_t*)(out + 70000000);       // qkv_w bf16 (out-slab scratch)
  ushort_t* bmf = (ushort_t*)d_ws;                   // [2401][12] bf16 flat bias

  k_cvt<<<(OUTSZ / 8 + 255) / 256, 256, 0, stream>>>(x, Xb, OUTSZ / 8);
  k_cvt<<<(3 * CDIM * CDIM / 8 + 255) / 256, 256, 0, stream>>>(qkv_w, Wb, 3 * CDIM * CDIM / 8);
  k_bias2<<<(NPT * 12 + 255) / 256, 256, 0, stream>>>(rpb, plw, plb, relidx, bmf);

  k_qkv_mfma<<<(BTOT * TOK / 128) * 9, 256, 0, stream>>>(Xb, Wb, qkv_b, qslab);

  k_attn9<<<BTOT * 2, 1024, 0, stream>>>(qslab, kslab, vslab, mask, bmf,
                                         plw, pww, pwb, out);

  k_proj3<<<BTOT * TOK / 64, 512, 0, stream>>>(out, projw, projb);
}

// Round 18
// 1319.181 us; speedup vs baseline: 1.0412x; 1.0085x over previous
//
#include <hip/hip_runtime.h>
#include <hip/hip_bf16.h>

#define TOK 49
#define NPT 2401                  // TOK*TOK
#define CDIM 384
#define NH 12
#define HDIM 32
#define NWIN 64
#define BTOT 4096
#define OUTSZ (BTOT * TOK * CDIM) // 77,070,336 floats per slab
#define L2E 1.4426950408889634f

typedef __attribute__((ext_vector_type(8))) short bf16x8;
typedef __attribute__((ext_vector_type(4))) float f32x4;
typedef unsigned int uint32;
typedef unsigned short ushort_t;

__device__ inline ushort_t f2bf(float f) {          // RNE fp32 -> bf16
  uint32 u = __float_as_uint(f);
  u += 0x7FFF + ((u >> 16) & 1);
  return (ushort_t)(u >> 16);
}
__device__ inline uint32 pk2(float a, float b) {    // v_cvt_pk_bf16_f32
  union { __hip_bfloat162 h; uint32 u; } x;
  x.h = __float22bfloat162_rn(float2{a, b});
  return x.u;
}
__device__ inline float bf2f(uint32 u) { return __uint_as_float((u & 0xffffu) << 16); }
__device__ inline bf16x8 pack8(float4 a, float4 b) {
  union { __hip_bfloat162 h[4]; bf16x8 v; } u;
  u.h[0] = __float22bfloat162_rn(float2{a.x, a.y});
  u.h[1] = __float22bfloat162_rn(float2{a.z, a.w});
  u.h[2] = __float22bfloat162_rn(float2{b.x, b.y});
  u.h[3] = __float22bfloat162_rn(float2{b.z, b.w});
  return u.v;
}
__device__ inline bf16x8 pack8f(const float* f) {
  union { __hip_bfloat162 h[4]; bf16x8 v; } u;
#pragma unroll
  for (int i = 0; i < 4; ++i) u.h[i] = __float22bfloat162_rn(float2{f[2*i], f[2*i+1]});
  return u.v;
}

// ---------------------------------------------------------------------------
// fp32 -> bf16 bulk convert (x, qkv_w)
// ---------------------------------------------------------------------------
__global__ void k_cvt(const float* __restrict__ src, ushort_t* __restrict__ dst, int n8) {
  int i = blockIdx.x * 256 + threadIdx.x;
  if (i >= n8) return;
  const float4* s = (const float4*)(src + (size_t)i * 8);
  float4 a = s[0], b = s[1];
  uint4 o;
  o.x = (uint32)f2bf(a.x) | ((uint32)f2bf(a.y) << 16);
  o.y = (uint32)f2bf(a.z) | ((uint32)f2bf(a.w) << 16);
  o.z = (uint32)f2bf(b.x) | ((uint32)f2bf(b.y) << 16);
  o.w = (uint32)f2bf(b.z) | ((uint32)f2bf(b.w) << 16);
  *(uint4*)(dst + (size_t)i * 8) = o;
}

// ---------------------------------------------------------------------------
// Flat bias (r17 path): bmf[p][g] = (plb[g]+sum plw*rpb[relidx[p]])*log2e
// ---------------------------------------------------------------------------
__global__ void k_bias2(const float* __restrict__ rpb, const float* __restrict__ plw,
                        const float* __restrict__ plb, const int* __restrict__ relidx,
                        ushort_t* __restrict__ bmf) {
  int i = blockIdx.x * 256 + threadIdx.x;
  if (i >= NPT * 12) return;
  int p = i / 12, g = i - (i / 12) * 12;
  int rid = relidx[p];
  float s = plb[g];
#pragma unroll
  for (int h = 0; h < NH; ++h) s = fmaf(plw[g * NH + h], rpb[rid * NH + h], s);
  bmf[i] = f2bf(s * L2E);
}

// ---------------------------------------------------------------------------
// Per-window folded table: bmfw[w][p][g] = (bias + mask[w][p]) * log2e
// 64*2401*12 bf16 = 3.69 MB; L3-resident, shared by all attn blocks.
// ---------------------------------------------------------------------------
__global__ void k_bias3(const float* __restrict__ rpb, const float* __restrict__ plw,
                        const float* __restrict__ plb, const int* __restrict__ relidx,
                        const float* __restrict__ mask, ushort_t* __restrict__ bmfw) {
  int i = blockIdx.x * 256 + threadIdx.x;
  if (i >= NWIN * NPT * 12) return;
  int w = i / (NPT * 12);
  int rem = i - w * (NPT * 12);
  int p = rem / 12, g = rem - (rem / 12) * 12;
  int rid = relidx[p];
  float s = plb[g];
#pragma unroll
  for (int h = 0; h < NH; ++h) s = fmaf(plw[g * NH + h], rpb[rid * NH + h], s);
  bmfw[i] = f2bf((s + mask[w * NPT + p]) * L2E);
}

// ---------------------------------------------------------------------------
// Kernel 1 (v4): QKV GEMM, bf16 MFMA, 128x128, BK=64, XOR-swizzled LDS.
// Barriers 24 -> 12; swizzle idx ^= (row&7)<<3 (16B slots) on BOTH staging
// write and fragment read -> 2-way (free) instead of 16-way conflicts.
// XCD-chunked strip-major swizzle kept (r13-verified).
// ---------------------------------------------------------------------------
__launch_bounds__(256)
__global__ void k_qkv_mfma(const ushort_t* __restrict__ Xb, const ushort_t* __restrict__ Wb,
                           const float* __restrict__ Bq, float* __restrict__ qslab) {
  __shared__ __align__(16) ushort_t As[128 * 64];   // 16 KB
  __shared__ __align__(16) ushort_t Bs[128 * 64];   // 16 KB
  const int bid = blockIdx.x;                 // 0..14111 (14112 % 8 == 0)
  const int sw = (bid & 7) * 1764 + (bid >> 3);
  const int bx = sw / 9;
  const int by = sw - bx * 9;
  const int tid = threadIdx.x;
  const int l = tid & 63, l15 = l & 15, l16 = l >> 4;
  const int wv = tid >> 6;
  const int wr = wv >> 1, wc = wv & 1;
  const int row0 = bx * 128;
  const int col0 = by * 128;

  f32x4 acc[4][4];
#pragma unroll
  for (int i = 0; i < 4; ++i)
#pragma unroll
    for (int j = 0; j < 4; ++j)
#pragma unroll
      for (int e = 0; e < 4; ++e) acc[i][j][e] = 0.f;

  const int sr = tid >> 3, sc = tid & 7;            // staging row/slot
  const int sidx = (sr * 64 + sc * 8) ^ ((sr & 7) << 3);

  for (int kb = 0; kb < CDIM; kb += 64) {
#pragma unroll
    for (int i = 0; i < 4; ++i) {
      int r = sr + i * 32;
      int idx = (sidx + i * 32 * 64) ^ 0;           // (r&7) invariant under +32
      uint4 v = *(const uint4*)&Xb[(size_t)(row0 + r) * CDIM + kb + sc * 8];
      *(uint4*)&As[idx] = v;
      uint4 w = *(const uint4*)&Wb[(size_t)(col0 + r) * CDIM + kb + sc * 8];
      *(uint4*)&Bs[idx] = w;
    }
    __syncthreads();
#pragma unroll
    for (int ks = 0; ks < 2; ++ks) {
      bf16x8 af[4], bfr[4];
#pragma unroll
      for (int mt = 0; mt < 4; ++mt) {
        int row = wr * 64 + mt * 16 + l15;
        af[mt] = *(const bf16x8*)&As[(row * 64 + ks * 32 + l16 * 8) ^ ((row & 7) << 3)];
      }
#pragma unroll
      for (int nt = 0; nt < 4; ++nt) {
        int row = wc * 64 + nt * 16 + l15;
        bfr[nt] = *(const bf16x8*)&Bs[(row * 64 + ks * 32 + l16 * 8) ^ ((row & 7) << 3)];
      }
#pragma unroll
      for (int mt = 0; mt < 4; ++mt)
#pragma unroll
        for (int nt = 0; nt < 4; ++nt)
          acc[mt][nt] = __builtin_amdgcn_mfma_f32_16x16x32_bf16(af[mt], bfr[nt], acc[mt][nt], 0, 0, 0);
    }
    __syncthreads();
  }

  const int slab = by / 3;
  const int cslab0 = col0 - slab * CDIM;
  float* dst = qslab + (size_t)slab * OUTSZ;
#pragma unroll
  for (int nt = 0; nt < 4; ++nt) {
    int colg = col0 + wc * 64 + nt * 16 + l15;
    int colo = cslab0 + wc * 64 + nt * 16 + l15;
    float bv = Bq[colg];
#pragma unroll
    for (int mt = 0; mt < 4; ++mt) {
      int rbase = row0 + wr * 64 + mt * 16 + l16 * 4;
#pragma unroll
      for (int j = 0; j < 4; ++j)
        dst[(size_t)(rbase + j) * CDIM + colo] = acc[mt][nt][j] + bv;
    }
  }
}

// ---------------------------------------------------------------------------
// Kernel 2 (v9c): r17's attn9; bias table indexed per-window (wstride=NPT*12,
// mask==nullptr) when ws permits, else shared table + mask add (r17 path).
// ---------------------------------------------------------------------------
__launch_bounds__(1024, 8)
__global__ void k_attn9(const float* __restrict__ qslab, const float* __restrict__ kslab,
                        const float* __restrict__ vslab, const float* __restrict__ mask,
                        const ushort_t* __restrict__ bmf, int wstride,
                        const float* __restrict__ plw, const float* __restrict__ pww,
                        const float* __restrict__ pwb, float* __restrict__ xout) {
  __shared__ __align__(16) ushort_t SA[19976];            // 39,952 B (S/P -> Vt)
  __shared__ __align__(16) ushort_t PP[12 * 1400 + 416];  // 34,432 B

  const int tid = threadIdx.x;
  const int b  = blockIdx.x >> 1;
  const int bh = blockIdx.x & 1;
  const int n0 = bh * 25;
  const int NR = bh ? 24 : 25;
  const size_t base = (size_t)b * TOK * CDIM;
  const int l = tid & 63, l15 = l & 15, l16 = l >> 4;
  const int wv = tid >> 6;                // 0..15
  const float SCL = 0.17677669529663687f * L2E;

  // ---- preamble: zero S h-slots 12..15 + phantom tail rows
  for (int p = tid; p < 1240; p += 1024) *(uint2*)&SA[p * 16 + 12] = uint2{0u, 0u};
  if (tid < 580) *(uint32*)&SA[18816 + tid * 2] = 0u;   // pts 1176..1239 + tail pad
  if (tid < 208) *(uint32*)&PP[12 * 1400 + tid * 2] = 0u;

  // ---- Phase A: S[pl][h] = raw q.k for this block's rows
  {
    const int art = wv >> 3;           // 0..1 local n-tile
    const int act = (wv >> 1) & 3;     // m-tile
    const int ah0 = (wv & 1) * 6;      // head half
    const int nrow = art * 16 + l15;
    const int mrow = act * 16 + l15;
    const bool qv = nrow < NR;
    const bool kv = mrow < TOK;
#pragma unroll
    for (int hp = 0; hp < 3; ++hp) {
      f32x4 s2[2];
#pragma unroll
      for (int hh = 0; hh < 2; ++hh) {
        int h = ah0 + hp * 2 + hh;
        bf16x8 af = {0,0,0,0,0,0,0,0}, bf = {0,0,0,0,0,0,0,0};
        if (qv) {
          const float4* qp = (const float4*)(qslab + base + (size_t)(n0 + nrow) * CDIM + h * HDIM + l16 * 8);
          af = pack8(qp[0], qp[1]);
        }
        if (kv) {
          const float4* kp = (const float4*)(kslab + base + (size_t)mrow * CDIM + h * HDIM + l16 * 8);
          bf = pack8(kp[0], kp[1]);
        }
        f32x4 z = {0.f, 0.f, 0.f, 0.f};
        s2[hh] = __builtin_amdgcn_mfma_f32_16x16x32_bf16(af, bf, z, 0, 0, 0);
      }
#pragma unroll
      for (int j = 0; j < 4; ++j) {
        int nj = art * 16 + l16 * 4 + j;
        if (nj < NR && kv)
          *(uint32*)&SA[(nj * 49 + mrow) * 16 + ah0 + hp * 2] = pk2(s2[0][j], s2[1][j]);
      }
    }
  }
  __syncthreads();   // b1

  // ---- per-row: mix1 + softmax + mix2 (rows nl = wv, wv+16 while < NR)
  {
    const float* maskw = mask ? (mask + (size_t)(b & (NWIN - 1)) * NPT) : nullptr;
    const ushort_t* bmw = bmf + (size_t)(b & (NWIN - 1)) * wstride;
    float apf[8], bpf[8];
#pragma unroll
    for (int j = 0; j < 8; ++j) {
      int kj = l16 * 8 + j;
      apf[j] = (l15 < NH && kj < NH) ? plw[l15 * NH + kj] * SCL : 0.f;
      bpf[j] = (l15 < NH && kj < NH) ? pww[l15 * NH + kj] : 0.f;
    }
    const bf16x8 aplw = pack8f(apf);
    const bf16x8 bpww = pack8f(bpf);
    const float pwbv = (l15 < NH) ? pwb[l15] : 0.f;

    for (int nl = wv; nl < NR; nl += 16) {
      const int pb0 = nl * 49;
      float ev[4][4];
      float rs[4] = {0.f, 0.f, 0.f, 0.f};
#pragma unroll
      for (int mc = 0; mc < 4; ++mc) {
        int m = mc * 16 + l15;
        int pl = pb0 + m;                         // <= 1239 (pads zeroed)
        bf16x8 sf = {0,0,0,0,0,0,0,0};            // K 16..31 MUST be 0
        if (l16 < 2) sf = *(const bf16x8*)&SA[pl * 16 + l16 * 8];
        int pg = pl + n0 * 49; if (pg > 2400) pg = 2400;
        uint2 bmu = *(const uint2*)&bmw[pg * 12 + l16 * 4];
        f32x4 cini = {bf2f(bmu.x), bf2f(bmu.x >> 16), bf2f(bmu.y), bf2f(bmu.y >> 16)};
        if (maskw) {
          float mk = maskw[pg] * L2E;
          cini[0] += mk; cini[1] += mk; cini[2] += mk; cini[3] += mk;
        }
        f32x4 o = __builtin_amdgcn_mfma_f32_16x16x32_bf16(aplw, sf, cini, 0, 0, 0);
        bool okm = (m < TOK);
#pragma unroll
        for (int j = 0; j < 4; ++j) {
          int g = l16 * 4 + j;
          float e = (okm && g < NH) ? exp2f(o[j]) : 0.f;
          ev[mc][j] = e;
          rs[j] += e;
        }
      }
#pragma unroll
      for (int d = 1; d < 16; d <<= 1)
#pragma unroll
        for (int j = 0; j < 4; ++j) rs[j] += __shfl_xor(rs[j], d, 64);
      float inv[4];
#pragma unroll
      for (int j = 0; j < 4; ++j) inv[j] = (rs[j] > 0.f) ? 1.f / rs[j] : 0.f;

      // P in place over S (own row only)
#pragma unroll
      for (int mc = 0; mc < 4; ++mc) {
        int m = mc * 16 + l15;
        if (m < TOK) {
          uint2 w;
          w.x = pk2(ev[mc][0] * inv[0], ev[mc][1] * inv[1]);
          w.y = pk2(ev[mc][2] * inv[2], ev[mc][3] * inv[3]);
          *(uint2*)&SA[(pb0 + m) * 16 + l16 * 4] = w;
        }
      }
      // mix2: rows=m, cols=g'
#pragma unroll
      for (int mc = 0; mc < 4; ++mc) {
        bf16x8 pf8 = {0,0,0,0,0,0,0,0};           // K 16..31 MUST be 0
        if (l16 < 2) pf8 = *(const bf16x8*)&SA[(pb0 + mc * 16 + l15) * 16 + l16 * 8];
        f32x4 cd = {pwbv, pwbv, pwbv, pwbv};
        f32x4 o = __builtin_amdgcn_mfma_f32_16x16x32_bf16(pf8, bpww, cd, 0, 0, 0);
        int m0 = mc * 16 + l16 * 4;
        if (l15 < NH && m0 < 56) {
          float z0 = (m0     < TOK) ? o[0] : 0.f;
          float z1 = (m0 + 1 < TOK) ? o[1] : 0.f;
          float z2 = (m0 + 2 < TOK) ? o[2] : 0.f;
          float z3 = (m0 + 3 < TOK) ? o[3] : 0.f;
          uint2 w;
          w.x = pk2(z0, z1);
          w.y = pk2(z2, z3);
          *(uint2*)&PP[l15 * 1400 + nl * 56 + m0] = w;
        }
      }
    }
  }
  __syncthreads();   // b2 (SA's P-copy now dead; PP holds P')

  // ---- Vt staging into SA region: Vt[c][m], stride 52, m=49..51 zeroed
  {
    ushort_t* Vt = SA;
    for (int i = tid; i < CDIM * 13; i += 1024) {
      int mq = i / CDIM, c = i - mq * CDIM;
      int m = mq * 4;
      float f0 = (m     < TOK) ? vslab[base + (size_t)(m    ) * CDIM + c] : 0.f;
      float f1 = (m + 1 < TOK) ? vslab[base + (size_t)(m + 1) * CDIM + c] : 0.f;
      float f2 = (m + 2 < TOK) ? vslab[base + (size_t)(m + 2) * CDIM + c] : 0.f;
      float f3 = (m + 3 < TOK) ? vslab[base + (size_t)(m + 3) * CDIM + c] : 0.f;
      uint2 u;
      u.x = pk2(f0, f1);
      u.y = pk2(f2, f3);
      *(uint2*)&Vt[c * 52 + mq * 4] = u;
    }
  }
  __syncthreads();   // b3

  // ---- Phase E: PV; wave=(ert, edt, egq) -> 3 heads; V from Vt (b64 pairs)
  {
    const ushort_t* Vt = SA;
    const int ert = wv >> 3;
    const int edt = (wv >> 2) & 1;
    const int egq = wv & 3;
#pragma unroll
    for (int gi = 0; gi < 3; ++gi) {
      int g = egq * 3 + gi;
      int col = g * HDIM + edt * 16 + l15;
      f32x4 acc = {0.f, 0.f, 0.f, 0.f};
#pragma unroll
      for (int ks = 0; ks < 2; ++ks) {
        bf16x8 pa8 = {0,0,0,0,0,0,0,0};
        bf16x8 vb8 = {0,0,0,0,0,0,0,0};
        if (!(ks == 1 && l16 == 3)) {             // k-slots 56..63 virtual pad
          pa8 = *(const bf16x8*)&PP[g * 1400 + (ert * 16 + l15) * 56 + ks * 32 + l16 * 8];
          uint2 lo = *(const uint2*)&Vt[col * 52 + ks * 32 + l16 * 8];
          uint2 hi = *(const uint2*)&Vt[col * 52 + ks * 32 + l16 * 8 + 4];
          union { uint32 u[4]; bf16x8 v; } uv;
          uv.u[0] = lo.x; uv.u[1] = lo.y; uv.u[2] = hi.x; uv.u[3] = hi.y;
          vb8 = uv.v;
        }
        acc = __builtin_amdgcn_mfma_f32_16x16x32_bf16(pa8, vb8, acc, 0, 0, 0);
      }
#pragma unroll
      for (int j = 0; j < 4; ++j) {
        int nlo = ert * 16 + l16 * 4 + j;
        if (nlo < NR)
          xout[base + (size_t)(n0 + nlo) * CDIM + col] = acc[j];
      }
    }
  }
}

// ---------------------------------------------------------------------------
// Kernel 3 (v3): output projection, 64-row strips, W LDS-staged (verified).
// ---------------------------------------------------------------------------
__launch_bounds__(512, 4)
__global__ void k_proj3(float* __restrict__ Y, const float* __restrict__ W,
                        const float* __restrict__ Bv) {
  __shared__ __align__(16) ushort_t Asb[64 * 392];   // 50,176 B
  __shared__ __align__(16) ushort_t Bsb[384 * 40];   // 30,720 B
  const int tid = threadIdx.x;
  const int l = tid & 63, l15 = l & 15, l16 = l >> 4;
  const int wv = tid >> 6;
  const int wr = wv >> 2;
  const int wc = wv & 3;
  const int row0 = blockIdx.x * 64;

#pragma unroll
  for (int i = 0; i < 6; ++i) {
    int cid = tid + i * 512;
    int r = cid / 48, c8 = cid - (cid / 48) * 48;
    const float4* s = (const float4*)&Y[(size_t)(row0 + r) * CDIM + c8 * 8];
    float4 a = s[0], b = s[1];
    uint4 o;
    o.x = pk2(a.x, a.y); o.y = pk2(a.z, a.w);
    o.z = pk2(b.x, b.y); o.w = pk2(b.z, b.w);
    *(uint4*)&Asb[r * 392 + c8 * 8] = o;
  }

  f32x4 acc[2][6];
#pragma unroll
  for (int i = 0; i < 2; ++i)
#pragma unroll
    for (int j = 0; j < 6; ++j)
#pragma unroll
      for (int e = 0; e < 4; ++e) acc[i][j][e] = 0.f;

  for (int kb = 0; kb < 12; ++kb) {
    __syncthreads();
#pragma unroll
    for (int i = 0; i < 3; ++i) {
      int cid = tid + i * 512;
      int col = cid >> 2, k8 = cid & 3;
      const float4* s = (const float4*)&W[(size_t)col * CDIM + kb * 32 + k8 * 8];
      float4 a = s[0], b = s[1];
      uint4 o;
      o.x = pk2(a.x, a.y); o.y = pk2(a.z, a.w);
      o.z = pk2(b.x, b.y); o.w = pk2(b.z, b.w);
      *(uint4*)&Bsb[col * 40 + k8 * 8] = o;
    }
    __syncthreads();
    bf16x8 af[2], bfr[6];
#pragma unroll
    for (int mt = 0; mt < 2; ++mt)
      af[mt] = *(const bf16x8*)&Asb[(wr * 32 + mt * 16 + l15) * 392 + kb * 32 + l16 * 8];
#pragma unroll
    for (int nt = 0; nt < 6; ++nt)
      bfr[nt] = *(const bf16x8*)&Bsb[(wc * 96 + nt * 16 + l15) * 40 + l16 * 8];
#pragma unroll
    for (int mt = 0; mt < 2; ++mt)
#pragma unroll
      for (int nt = 0; nt < 6; ++nt)
        acc[mt][nt] = __builtin_amdgcn_mfma_f32_16x16x32_bf16(af[mt], bfr[nt], acc[mt][nt], 0, 0, 0);
  }

#pragma unroll
  for (int nt = 0; nt < 6; ++nt) {
    int col = wc * 96 + nt * 16 + l15;
    float bv = Bv[col];
#pragma unroll
    for (int mt = 0; mt < 2; ++mt) {
      int rbase = row0 + wr * 32 + mt * 16 + l16 * 4;
#pragma unroll
      for (int j = 0; j < 4; ++j)
        Y[(size_t)(rbase + j) * CDIM + col] = acc[mt][nt][j] + bv;
    }
  }
}

// ---------------------------------------------------------------------------
extern "C" void kernel_launch(void* const* d_in, const int* in_sizes, int n_in,
                              void* d_out, int out_size, void* d_ws, size_t ws_size,
                              hipStream_t stream) {
  const float* x      = (const float*)d_in[0];
  const float* mask   = (const float*)d_in[1];
  const float* qkv_w  = (const float*)d_in[2];
  const float* qkv_b  = (const float*)d_in[3];
  const float* rpb    = (const float*)d_in[4];
  const float* plw    = (const float*)d_in[5];
  const float* plb    = (const float*)d_in[6];
  const float* pww    = (const float*)d_in[7];
  const float* pwb    = (const float*)d_in[8];
  const float* projw  = (const float*)d_in[9];
  const float* projb  = (const float*)d_in[10];
  const int*   relidx = (const int*)d_in[11];

  float* out   = (float*)d_out;
  float* qslab = out + (size_t)OUTSZ;
  float* kslab = out + 2 * (size_t)OUTSZ;
  float* vslab = out + 3 * (size_t)OUTSZ;

  ushort_t* Xb  = (ushort_t*)out;                    // x bf16 (out-slab scratch)
  ushort_t* Wb  = (ushort_t*)(out + 70000000);       // qkv_w bf16 (out-slab scratch)
  ushort_t* bmf = (ushort_t*)d_ws;                   // bias table (flat or per-window)

  k_cvt<<<(OUTSZ / 8 + 255) / 256, 256, 0, stream>>>(x, Xb, OUTSZ / 8);
  k_cvt<<<(3 * CDIM * CDIM / 8 + 255) / 256, 256, 0, stream>>>(qkv_w, Wb, 3 * CDIM * CDIM / 8);

  const size_t need_ws = (size_t)NWIN * NPT * 12 * sizeof(ushort_t);
  const bool folded = (ws_size >= need_ws);
  if (folded)
    k_bias3<<<(NWIN * NPT * 12 + 255) / 256, 256, 0, stream>>>(rpb, plw, plb, relidx, mask, bmf);
  else
    k_bias2<<<(NPT * 12 + 255) / 256, 256, 0, stream>>>(rpb, plw, plb, relidx, bmf);

  k_qkv_mfma<<<(BTOT * TOK / 128) * 9, 256, 0, stream>>>(Xb, Wb, qkv_b, qslab);

  k_attn9<<<BTOT * 2, 1024, 0, stream>>>(qslab, kslab, vslab,
                                         folded ? nullptr : mask, bmf,
                                         folded ? NPT * 12 : 0,
                                         plw, pww, pwb, out);

  k_proj3<<<BTOT * TOK / 64, 512, 0, stream>>>(out, projw, projb);
}

// Round 19
// 1246.425 us; speedup vs baseline: 1.1020x; 1.0584x over previous
//
#include <hip/hip_runtime.h>
#include <hip/hip_bf16.h>

#define TOK 49
#define NPT 2401                  // TOK*TOK
#define CDIM 384
#define NH 12
#define HDIM 32
#define NWIN 64
#define BTOT 4096
#define OUTSZ (BTOT * TOK * CDIM) // 77,070,336 floats per slab
#define L2E 1.4426950408889634f

typedef __attribute__((ext_vector_type(8))) short bf16x8;
typedef __attribute__((ext_vector_type(4))) float f32x4;
typedef unsigned int uint32;
typedef unsigned short ushort_t;

__device__ inline ushort_t f2bf(float f) {          // RNE fp32 -> bf16
  uint32 u = __float_as_uint(f);
  u += 0x7FFF + ((u >> 16) & 1);
  return (ushort_t)(u >> 16);
}
__device__ inline uint32 pk2(float a, float b) {    // v_cvt_pk_bf16_f32
  union { __hip_bfloat162 h; uint32 u; } x;
  x.h = __float22bfloat162_rn(float2{a, b});
  return x.u;
}
__device__ inline float bf2f(uint32 u) { return __uint_as_float((u & 0xffffu) << 16); }
__device__ inline bf16x8 pack8(float4 a, float4 b) {
  union { __hip_bfloat162 h[4]; bf16x8 v; } u;
  u.h[0] = __float22bfloat162_rn(float2{a.x, a.y});
  u.h[1] = __float22bfloat162_rn(float2{a.z, a.w});
  u.h[2] = __float22bfloat162_rn(float2{b.x, b.y});
  u.h[3] = __float22bfloat162_rn(float2{b.z, b.w});
  return u.v;
}
__device__ inline bf16x8 pack8f(const float* f) {
  union { __hip_bfloat162 h[4]; bf16x8 v; } u;
#pragma unroll
  for (int i = 0; i < 4; ++i) u.h[i] = __float22bfloat162_rn(float2{f[2*i], f[2*i+1]});
  return u.v;
}

// ---------------------------------------------------------------------------
// fp32 -> bf16 bulk convert (qkv_w only now)
// ---------------------------------------------------------------------------
__global__ void k_cvt(const float* __restrict__ src, ushort_t* __restrict__ dst, int n8) {
  int i = blockIdx.x * 256 + threadIdx.x;
  if (i >= n8) return;
  const float4* s = (const float4*)(src + (size_t)i * 8);
  float4 a = s[0], b = s[1];
  uint4 o;
  o.x = (uint32)f2bf(a.x) | ((uint32)f2bf(a.y) << 16);
  o.y = (uint32)f2bf(a.z) | ((uint32)f2bf(a.w) << 16);
  o.z = (uint32)f2bf(b.x) | ((uint32)f2bf(b.y) << 16);
  o.w = (uint32)f2bf(b.z) | ((uint32)f2bf(b.w) << 16);
  *(uint4*)(dst + (size_t)i * 8) = o;
}

// ---------------------------------------------------------------------------
// Flat bias (fallback): bmf[p][g] = (plb[g]+sum plw*rpb[relidx[p]])*log2e
// ---------------------------------------------------------------------------
__global__ void k_bias2(const float* __restrict__ rpb, const float* __restrict__ plw,
                        const float* __restrict__ plb, const int* __restrict__ relidx,
                        ushort_t* __restrict__ bmf) {
  int i = blockIdx.x * 256 + threadIdx.x;
  if (i >= NPT * 12) return;
  int p = i / 12, g = i - (i / 12) * 12;
  int rid = relidx[p];
  float s = plb[g];
#pragma unroll
  for (int h = 0; h < NH; ++h) s = fmaf(plw[g * NH + h], rpb[rid * NH + h], s);
  bmf[i] = f2bf(s * L2E);
}

// ---------------------------------------------------------------------------
// Per-window folded table: bmfw[w][p][g] = (bias + mask[w][p]) * log2e
// ---------------------------------------------------------------------------
__global__ void k_bias3(const float* __restrict__ rpb, const float* __restrict__ plw,
                        const float* __restrict__ plb, const int* __restrict__ relidx,
                        const float* __restrict__ mask, ushort_t* __restrict__ bmfw) {
  int i = blockIdx.x * 256 + threadIdx.x;
  if (i >= NWIN * NPT * 12) return;
  int w = i / (NPT * 12);
  int rem = i - w * (NPT * 12);
  int p = rem / 12, g = rem - (rem / 12) * 12;
  int rid = relidx[p];
  float s = plb[g];
#pragma unroll
  for (int h = 0; h < NH; ++h) s = fmaf(plw[g * NH + h], rpb[rid * NH + h], s);
  bmfw[i] = f2bf((s + mask[w * NPT + p]) * L2E);
}

// ---------------------------------------------------------------------------
// Kernel 1 (v5): single-pass QKV. Block = 64-row X panel staged fp32->bf16
// into LDS ONCE (X read exactly once from HBM; k_cvt(x) eliminated), then
// an in-block loop over the 9 col-blocks with ZERO K-loop barriers: W read
// as bf16 fragments direct from global (884 KB, L2-resident per XCD).
// 256 thr = 4 waves (wc 0..3), wave = 64 rows x 32 cols per col-block.
// 50 KB LDS -> 3 blocks/CU. Panel-contiguous XCD swizzle (3136 = 8*392).
// ---------------------------------------------------------------------------
__launch_bounds__(256)
__global__ void k_qkv_mega(const float* __restrict__ X, const ushort_t* __restrict__ Wb,
                           const float* __restrict__ Bq, float* __restrict__ qslab) {
  __shared__ __align__(16) ushort_t Xs[64 * 392];   // 50,176 B
  const int bid = blockIdx.x;                 // 0..3135
  const int sw = (bid & 7) * 392 + (bid >> 3);
  const int row0 = sw * 64;
  const int tid = threadIdx.x;
  const int l = tid & 63, l15 = l & 15, l16 = l >> 4;
  const int wc = tid >> 6;                    // 0..3

  // stage the 64x384 X panel once, fp32 -> bf16
#pragma unroll
  for (int i = 0; i < 12; ++i) {
    int cid = tid + i * 256;                  // 0..3071 chunks of 8
    int r = cid / 48, c8 = cid - (cid / 48) * 48;
    const float4* s = (const float4*)&X[(size_t)(row0 + r) * CDIM + c8 * 8];
    float4 a = s[0], b = s[1];
    uint4 o;
    o.x = pk2(a.x, a.y); o.y = pk2(a.z, a.w);
    o.z = pk2(b.x, b.y); o.w = pk2(b.z, b.w);
    *(uint4*)&Xs[r * 392 + c8 * 8] = o;
  }
  __syncthreads();                            // the only barrier

  for (int by = 0; by < 9; ++by) {
    f32x4 acc[4][2];
#pragma unroll
    for (int mt = 0; mt < 4; ++mt)
#pragma unroll
      for (int nt = 0; nt < 2; ++nt)
#pragma unroll
        for (int e = 0; e < 4; ++e) acc[mt][nt][e] = 0.f;

#pragma unroll 2
    for (int ks = 0; ks < 12; ++ks) {
      bf16x8 af[4], bfr[2];
#pragma unroll
      for (int mt = 0; mt < 4; ++mt)
        af[mt] = *(const bf16x8*)&Xs[(mt * 16 + l15) * 392 + ks * 32 + l16 * 8];
#pragma unroll
      for (int nt = 0; nt < 2; ++nt)
        bfr[nt] = *(const bf16x8*)&Wb[(size_t)(by * 128 + wc * 32 + nt * 16 + l15) * CDIM + ks * 32 + l16 * 8];
#pragma unroll
      for (int mt = 0; mt < 4; ++mt)
#pragma unroll
        for (int nt = 0; nt < 2; ++nt)
          acc[mt][nt] = __builtin_amdgcn_mfma_f32_16x16x32_bf16(af[mt], bfr[nt], acc[mt][nt], 0, 0, 0);
    }

    const int slab = by / 3;
    const int cbase = (by - slab * 3) * 128;
    float* dst = qslab + (size_t)slab * OUTSZ;
#pragma unroll
    for (int nt = 0; nt < 2; ++nt) {
      int colg = by * 128 + wc * 32 + nt * 16 + l15;
      int colo = cbase + wc * 32 + nt * 16 + l15;
      float bv = Bq[colg];
#pragma unroll
      for (int mt = 0; mt < 4; ++mt) {
        int rbase = row0 + mt * 16 + l16 * 4;
#pragma unroll
        for (int j = 0; j < 4; ++j)
          dst[(size_t)(rbase + j) * CDIM + colo] = acc[mt][nt][j] + bv;
      }
    }
  }
}

// ---------------------------------------------------------------------------
// Kernel 2 (v9c): attention (r18-verified; unchanged).
// ---------------------------------------------------------------------------
__launch_bounds__(1024, 8)
__global__ void k_attn9(const float* __restrict__ qslab, const float* __restrict__ kslab,
                        const float* __restrict__ vslab, const float* __restrict__ mask,
                        const ushort_t* __restrict__ bmf, int wstride,
                        const float* __restrict__ plw, const float* __restrict__ pww,
                        const float* __restrict__ pwb, float* __restrict__ xout) {
  __shared__ __align__(16) ushort_t SA[19976];            // 39,952 B (S/P -> Vt)
  __shared__ __align__(16) ushort_t PP[12 * 1400 + 416];  // 34,432 B

  const int tid = threadIdx.x;
  const int b  = blockIdx.x >> 1;
  const int bh = blockIdx.x & 1;
  const int n0 = bh * 25;
  const int NR = bh ? 24 : 25;
  const size_t base = (size_t)b * TOK * CDIM;
  const int l = tid & 63, l15 = l & 15, l16 = l >> 4;
  const int wv = tid >> 6;                // 0..15
  const float SCL = 0.17677669529663687f * L2E;

  for (int p = tid; p < 1240; p += 1024) *(uint2*)&SA[p * 16 + 12] = uint2{0u, 0u};
  if (tid < 580) *(uint32*)&SA[18816 + tid * 2] = 0u;   // pts 1176..1239 + tail pad
  if (tid < 208) *(uint32*)&PP[12 * 1400 + tid * 2] = 0u;

  // ---- Phase A: S[pl][h] = raw q.k for this block's rows
  {
    const int art = wv >> 3;
    const int act = (wv >> 1) & 3;
    const int ah0 = (wv & 1) * 6;
    const int nrow = art * 16 + l15;
    const int mrow = act * 16 + l15;
    const bool qv = nrow < NR;
    const bool kv = mrow < TOK;
#pragma unroll
    for (int hp = 0; hp < 3; ++hp) {
      f32x4 s2[2];
#pragma unroll
      for (int hh = 0; hh < 2; ++hh) {
        int h = ah0 + hp * 2 + hh;
        bf16x8 af = {0,0,0,0,0,0,0,0}, bf = {0,0,0,0,0,0,0,0};
        if (qv) {
          const float4* qp = (const float4*)(qslab + base + (size_t)(n0 + nrow) * CDIM + h * HDIM + l16 * 8);
          af = pack8(qp[0], qp[1]);
        }
        if (kv) {
          const float4* kp = (const float4*)(kslab + base + (size_t)mrow * CDIM + h * HDIM + l16 * 8);
          bf = pack8(kp[0], kp[1]);
        }
        f32x4 z = {0.f, 0.f, 0.f, 0.f};
        s2[hh] = __builtin_amdgcn_mfma_f32_16x16x32_bf16(af, bf, z, 0, 0, 0);
      }
#pragma unroll
      for (int j = 0; j < 4; ++j) {
        int nj = art * 16 + l16 * 4 + j;
        if (nj < NR && kv)
          *(uint32*)&SA[(nj * 49 + mrow) * 16 + ah0 + hp * 2] = pk2(s2[0][j], s2[1][j]);
      }
    }
  }
  __syncthreads();   // b1

  // ---- per-row: mix1 + softmax + mix2
  {
    const float* maskw = mask ? (mask + (size_t)(b & (NWIN - 1)) * NPT) : nullptr;
    const ushort_t* bmw = bmf + (size_t)(b & (NWIN - 1)) * wstride;
    float apf[8], bpf[8];
#pragma unroll
    for (int j = 0; j < 8; ++j) {
      int kj = l16 * 8 + j;
      apf[j] = (l15 < NH && kj < NH) ? plw[l15 * NH + kj] * SCL : 0.f;
      bpf[j] = (l15 < NH && kj < NH) ? pww[l15 * NH + kj] : 0.f;
    }
    const bf16x8 aplw = pack8f(apf);
    const bf16x8 bpww = pack8f(bpf);
    const float pwbv = (l15 < NH) ? pwb[l15] : 0.f;

    for (int nl = wv; nl < NR; nl += 16) {
      const int pb0 = nl * 49;
      float ev[4][4];
      float rs[4] = {0.f, 0.f, 0.f, 0.f};
#pragma unroll
      for (int mc = 0; mc < 4; ++mc) {
        int m = mc * 16 + l15;
        int pl = pb0 + m;
        bf16x8 sf = {0,0,0,0,0,0,0,0};            // K 16..31 MUST be 0
        if (l16 < 2) sf = *(const bf16x8*)&SA[pl * 16 + l16 * 8];
        int pg = pl + n0 * 49; if (pg > 2400) pg = 2400;
        uint2 bmu = *(const uint2*)&bmw[pg * 12 + l16 * 4];
        f32x4 cini = {bf2f(bmu.x), bf2f(bmu.x >> 16), bf2f(bmu.y), bf2f(bmu.y >> 16)};
        if (maskw) {
          float mk = maskw[pg] * L2E;
          cini[0] += mk; cini[1] += mk; cini[2] += mk; cini[3] += mk;
        }
        f32x4 o = __builtin_amdgcn_mfma_f32_16x16x32_bf16(aplw, sf, cini, 0, 0, 0);
        bool okm = (m < TOK);
#pragma unroll
        for (int j = 0; j < 4; ++j) {
          int g = l16 * 4 + j;
          float e = (okm && g < NH) ? exp2f(o[j]) : 0.f;
          ev[mc][j] = e;
          rs[j] += e;
        }
      }
#pragma unroll
      for (int d = 1; d < 16; d <<= 1)
#pragma unroll
        for (int j = 0; j < 4; ++j) rs[j] += __shfl_xor(rs[j], d, 64);
      float inv[4];
#pragma unroll
      for (int j = 0; j < 4; ++j) inv[j] = (rs[j] > 0.f) ? 1.f / rs[j] : 0.f;

#pragma unroll
      for (int mc = 0; mc < 4; ++mc) {
        int m = mc * 16 + l15;
        if (m < TOK) {
          uint2 w;
          w.x = pk2(ev[mc][0] * inv[0], ev[mc][1] * inv[1]);
          w.y = pk2(ev[mc][2] * inv[2], ev[mc][3] * inv[3]);
          *(uint2*)&SA[(pb0 + m) * 16 + l16 * 4] = w;
        }
      }
#pragma unroll
      for (int mc = 0; mc < 4; ++mc) {
        bf16x8 pf8 = {0,0,0,0,0,0,0,0};           // K 16..31 MUST be 0
        if (l16 < 2) pf8 = *(const bf16x8*)&SA[(pb0 + mc * 16 + l15) * 16 + l16 * 8];
        f32x4 cd = {pwbv, pwbv, pwbv, pwbv};
        f32x4 o = __builtin_amdgcn_mfma_f32_16x16x32_bf16(pf8, bpww, cd, 0, 0, 0);
        int m0 = mc * 16 + l16 * 4;
        if (l15 < NH && m0 < 56) {
          float z0 = (m0     < TOK) ? o[0] : 0.f;
          float z1 = (m0 + 1 < TOK) ? o[1] : 0.f;
          float z2 = (m0 + 2 < TOK) ? o[2] : 0.f;
          float z3 = (m0 + 3 < TOK) ? o[3] : 0.f;
          uint2 w;
          w.x = pk2(z0, z1);
          w.y = pk2(z2, z3);
          *(uint2*)&PP[l15 * 1400 + nl * 56 + m0] = w;
        }
      }
    }
  }
  __syncthreads();   // b2

  // ---- Vt staging into SA region: Vt[c][m], stride 52, m=49..51 zeroed
  {
    ushort_t* Vt = SA;
    for (int i = tid; i < CDIM * 13; i += 1024) {
      int mq = i / CDIM, c = i - mq * CDIM;
      int m = mq * 4;
      float f0 = (m     < TOK) ? vslab[base + (size_t)(m    ) * CDIM + c] : 0.f;
      float f1 = (m + 1 < TOK) ? vslab[base + (size_t)(m + 1) * CDIM + c] : 0.f;
      float f2 = (m + 2 < TOK) ? vslab[base + (size_t)(m + 2) * CDIM + c] : 0.f;
      float f3 = (m + 3 < TOK) ? vslab[base + (size_t)(m + 3) * CDIM + c] : 0.f;
      uint2 u;
      u.x = pk2(f0, f1);
      u.y = pk2(f2, f3);
      *(uint2*)&Vt[c * 52 + mq * 4] = u;
    }
  }
  __syncthreads();   // b3

  // ---- Phase E: PV
  {
    const ushort_t* Vt = SA;
    const int ert = wv >> 3;
    const int edt = (wv >> 2) & 1;
    const int egq = wv & 3;
#pragma unroll
    for (int gi = 0; gi < 3; ++gi) {
      int g = egq * 3 + gi;
      int col = g * HDIM + edt * 16 + l15;
      f32x4 acc = {0.f, 0.f, 0.f, 0.f};
#pragma unroll
      for (int ks = 0; ks < 2; ++ks) {
        bf16x8 pa8 = {0,0,0,0,0,0,0,0};
        bf16x8 vb8 = {0,0,0,0,0,0,0,0};
        if (!(ks == 1 && l16 == 3)) {
          pa8 = *(const bf16x8*)&PP[g * 1400 + (ert * 16 + l15) * 56 + ks * 32 + l16 * 8];
          uint2 lo = *(const uint2*)&Vt[col * 52 + ks * 32 + l16 * 8];
          uint2 hi = *(const uint2*)&Vt[col * 52 + ks * 32 + l16 * 8 + 4];
          union { uint32 u[4]; bf16x8 v; } uv;
          uv.u[0] = lo.x; uv.u[1] = lo.y; uv.u[2] = hi.x; uv.u[3] = hi.y;
          vb8 = uv.v;
        }
        acc = __builtin_amdgcn_mfma_f32_16x16x32_bf16(pa8, vb8, acc, 0, 0, 0);
      }
#pragma unroll
      for (int j = 0; j < 4; ++j) {
        int nlo = ert * 16 + l16 * 4 + j;
        if (nlo < NR)
          xout[base + (size_t)(n0 + nlo) * CDIM + col] = acc[j];
      }
    }
  }
}

// ---------------------------------------------------------------------------
// Kernel 3 (v3): output projection (r18-verified; unchanged).
// ---------------------------------------------------------------------------
__launch_bounds__(512, 4)
__global__ void k_proj3(float* __restrict__ Y, const float* __restrict__ W,
                        const float* __restrict__ Bv) {
  __shared__ __align__(16) ushort_t Asb[64 * 392];   // 50,176 B
  __shared__ __align__(16) ushort_t Bsb[384 * 40];   // 30,720 B
  const int tid = threadIdx.x;
  const int l = tid & 63, l15 = l & 15, l16 = l >> 4;
  const int wv = tid >> 6;
  const int wr = wv >> 2;
  const int wc = wv & 3;
  const int row0 = blockIdx.x * 64;

#pragma unroll
  for (int i = 0; i < 6; ++i) {
    int cid = tid + i * 512;
    int r = cid / 48, c8 = cid - (cid / 48) * 48;
    const float4* s = (const float4*)&Y[(size_t)(row0 + r) * CDIM + c8 * 8];
    float4 a = s[0], b = s[1];
    uint4 o;
    o.x = pk2(a.x, a.y); o.y = pk2(a.z, a.w);
    o.z = pk2(b.x, b.y); o.w = pk2(b.z, b.w);
    *(uint4*)&Asb[r * 392 + c8 * 8] = o;
  }

  f32x4 acc[2][6];
#pragma unroll
  for (int i = 0; i < 2; ++i)
#pragma unroll
    for (int j = 0; j < 6; ++j)
#pragma unroll
      for (int e = 0; e < 4; ++e) acc[i][j][e] = 0.f;

  for (int kb = 0; kb < 12; ++kb) {
    __syncthreads();
#pragma unroll
    for (int i = 0; i < 3; ++i) {
      int cid = tid + i * 512;
      int col = cid >> 2, k8 = cid & 3;
      const float4* s = (const float4*)&W[(size_t)col * CDIM + kb * 32 + k8 * 8];
      float4 a = s[0], b = s[1];
      uint4 o;
      o.x = pk2(a.x, a.y); o.y = pk2(a.z, a.w);
      o.z = pk2(b.x, b.y); o.w = pk2(b.z, b.w);
      *(uint4*)&Bsb[col * 40 + k8 * 8] = o;
    }
    __syncthreads();
    bf16x8 af[2], bfr[6];
#pragma unroll
    for (int mt = 0; mt < 2; ++mt)
      af[mt] = *(const bf16x8*)&Asb[(wr * 32 + mt * 16 + l15) * 392 + kb * 32 + l16 * 8];
#pragma unroll
    for (int nt = 0; nt < 6; ++nt)
      bfr[nt] = *(const bf16x8*)&Bsb[(wc * 96 + nt * 16 + l15) * 40 + l16 * 8];
#pragma unroll
    for (int mt = 0; mt < 2; ++mt)
#pragma unroll
      for (int nt = 0; nt < 6; ++nt)
        acc[mt][nt] = __builtin_amdgcn_mfma_f32_16x16x32_bf16(af[mt], bfr[nt], acc[mt][nt], 0, 0, 0);
  }

#pragma unroll
  for (int nt = 0; nt < 6; ++nt) {
    int col = wc * 96 + nt * 16 + l15;
    float bv = Bv[col];
#pragma unroll
    for (int mt = 0; mt < 2; ++mt) {
      int rbase = row0 + wr * 32 + mt * 16 + l16 * 4;
#pragma unroll
      for (int j = 0; j < 4; ++j)
        Y[(size_t)(rbase + j) * CDIM + col] = acc[mt][nt][j] + bv;
    }
  }
}

// ---------------------------------------------------------------------------
extern "C" void kernel_launch(void* const* d_in, const int* in_sizes, int n_in,
                              void* d_out, int out_size, void* d_ws, size_t ws_size,
                              hipStream_t stream) {
  const float* x      = (const float*)d_in[0];
  const float* mask   = (const float*)d_in[1];
  const float* qkv_w  = (const float*)d_in[2];
  const float* qkv_b  = (const float*)d_in[3];
  const float* rpb    = (const float*)d_in[4];
  const float* plw    = (const float*)d_in[5];
  const float* plb    = (const float*)d_in[6];
  const float* pww    = (const float*)d_in[7];
  const float* pwb    = (const float*)d_in[8];
  const float* projw  = (const float*)d_in[9];
  const float* projb  = (const float*)d_in[10];
  const int*   relidx = (const int*)d_in[11];

  float* out   = (float*)d_out;
  float* qslab = out + (size_t)OUTSZ;
  float* kslab = out + 2 * (size_t)OUTSZ;
  float* vslab = out + 3 * (size_t)OUTSZ;

  ushort_t* Wb  = (ushort_t*)(out + 70000000);       // qkv_w bf16 (out-slab scratch)
  ushort_t* bmf = (ushort_t*)d_ws;                   // bias table (flat or per-window)

  k_cvt<<<(3 * CDIM * CDIM / 8 + 255) / 256, 256, 0, stream>>>(qkv_w, Wb, 3 * CDIM * CDIM / 8);

  const size_t need_ws = (size_t)NWIN * NPT * 12 * sizeof(ushort_t);
  const bool folded = (ws_size >= need_ws);
  if (folded)
    k_bias3<<<(NWIN * NPT * 12 + 255) / 256, 256, 0, stream>>>(rpb, plw, plb, relidx, mask, bmf);
  else
    k_bias2<<<(NPT * 12 + 255) / 256, 256, 0, stream>>>(rpb, plw, plb, relidx, bmf);

  k_qkv_mega<<<BTOT * TOK / 64, 256, 0, stream>>>(x, Wb, qkv_b, qslab);

  k_attn9<<<BTOT * 2, 1024, 0, stream>>>(qslab, kslab, vslab,
                                         folded ? nullptr : mask, bmf,
                                         folded ? NPT * 12 : 0,
                                         plw, pww, pwb, out);

  k_proj3<<<BTOT * TOK / 64, 512, 0, stream>>>(out, projw, projb);
}